// Round 1
// baseline (1216.729 us; speedup 1.0000x reference)
//
#include <hip/hip_runtime.h>
#include <math.h>

// GCNConv QNet: out = tanh( (segsum(x[src]*norm, dst) + selfloop) @ W1 + b1 ) @ W2 + b2
// with norm = dinv[src]*dinv[dst], dinv = rsqrt(in_degree + 1).
// Aggregation done in 32-dim obs space (W1 applied AFTER segment_sum — linearity).

#define NOBS 32
#define NMID 64
#define NACT 8

// Detect whether edge_index arrived as int64 (reference dtype) or int32
// (harness doc says integer -> const int*). For little-endian int64 values in
// [0, 2^31), every odd 32-bit word is zero. For genuine int32 random indices
// in [0,100000), the probability all four sampled words are zero is ~1e-20.
__device__ __forceinline__ bool edges_i64(const int* ei) {
    return (ei[1] | ei[3] | ei[5] | ei[7]) == 0;
}

__device__ __forceinline__ void load_edge(const int* ei, bool i64, long long e,
                                          long long idx, int& s, int& d) {
    if (i64) {
        const long long* e64 = (const long long*)ei;
        s = (int)e64[idx];
        d = (int)e64[e + idx];
    } else {
        s = ei[idx];
        d = ei[e + idx];
    }
}

__global__ void k_deg_init(float* __restrict__ deg, int n) {
    int i = blockIdx.x * blockDim.x + threadIdx.x;
    if (i < n) deg[i] = 1.0f;  // self-loop
}

__global__ void k_deg_count(const int* __restrict__ ei, float* __restrict__ deg, int e) {
    long long t = (long long)blockIdx.x * blockDim.x + threadIdx.x;
    if (t >= e) return;
    bool i64 = edges_i64(ei);
    int d;
    if (i64) d = (int)((const long long*)ei)[(long long)e + t];
    else     d = ei[(long long)e + t];
    atomicAdd(&deg[d], 1.0f);
}

// dinv = rsqrt(deg); agg[i][:] = x[i][:] * dinv[i]^2  (self-loop message)
__global__ void k_init_agg(const float* __restrict__ x, const float* __restrict__ deg,
                           float* __restrict__ dinv, float* __restrict__ agg, int n) {
    long long t = (long long)blockIdx.x * blockDim.x + threadIdx.x;
    if (t >= (long long)n * NOBS) return;
    int i = (int)(t >> 5);
    float r = rsqrtf(deg[i]);
    if ((t & 31) == 0) dinv[i] = r;
    agg[t] = x[t] * (r * r);
}

// 32 lanes per edge: coalesced gather of x[src] row + coalesced atomic burst to agg[dst]
__global__ void k_scatter(const int* __restrict__ ei, const float* __restrict__ x,
                          const float* __restrict__ dinv, float* __restrict__ agg, int e) {
    long long t = (long long)blockIdx.x * blockDim.x + threadIdx.x;
    if (t >= (long long)e * NOBS) return;
    int lane = (int)(t & 31);
    long long eidx = t >> 5;
    bool i64 = edges_i64(ei);
    int s, d;
    load_edge(ei, i64, e, eidx, s, d);
    float w = dinv[s] * dinv[d];
    float v = x[(long long)s * NOBS + lane] * w;
    atomicAdd(&agg[(long long)d * NOBS + lane], v);
}

// Per-node dense epilogue: out = tanh(agg @ W1 + b1) @ W2 + b2
__global__ __launch_bounds__(256) void k_final(
        const float* __restrict__ agg, const float* __restrict__ W1,
        const float* __restrict__ b1, const float* __restrict__ W2,
        const float* __restrict__ b2, float* __restrict__ out, int n) {
    __shared__ float sW1[NOBS * NMID];   // 8 KB
    __shared__ float sW2[NMID * NACT];   // 2 KB
    __shared__ float sb1[NMID];
    __shared__ float sb2[NACT];
    for (int j = threadIdx.x; j < NOBS * NMID; j += 256) sW1[j] = W1[j];
    for (int j = threadIdx.x; j < NMID * NACT; j += 256) sW2[j] = W2[j];
    if (threadIdx.x < NMID) sb1[threadIdx.x] = b1[threadIdx.x];
    if (threadIdx.x < NACT) sb2[threadIdx.x] = b2[threadIdx.x];
    __syncthreads();

    int i = blockIdx.x * 256 + threadIdx.x;
    if (i >= n) return;

    float m[NMID];
#pragma unroll
    for (int j = 0; j < NMID; ++j) m[j] = sb1[j];

    const float4* a4 = (const float4*)(agg + (size_t)i * NOBS);
#pragma unroll
    for (int f4 = 0; f4 < NOBS / 4; ++f4) {
        float4 a = a4[f4];
        float av[4] = {a.x, a.y, a.z, a.w};
#pragma unroll
        for (int c = 0; c < 4; ++c) {
            const float4* wrow = (const float4*)(sW1 + (f4 * 4 + c) * NMID);
#pragma unroll
            for (int j4 = 0; j4 < NMID / 4; ++j4) {
                float4 w = wrow[j4];
                m[j4 * 4 + 0] = fmaf(av[c], w.x, m[j4 * 4 + 0]);
                m[j4 * 4 + 1] = fmaf(av[c], w.y, m[j4 * 4 + 1]);
                m[j4 * 4 + 2] = fmaf(av[c], w.z, m[j4 * 4 + 2]);
                m[j4 * 4 + 3] = fmaf(av[c], w.w, m[j4 * 4 + 3]);
            }
        }
    }

    float o[NACT];
#pragma unroll
    for (int k = 0; k < NACT; ++k) o[k] = sb2[k];
#pragma unroll
    for (int j = 0; j < NMID; ++j) {
        float tj = tanhf(m[j]);
        const float4* w2r = (const float4*)(sW2 + j * NACT);
        float4 wa = w2r[0], wb = w2r[1];
        o[0] = fmaf(tj, wa.x, o[0]);
        o[1] = fmaf(tj, wa.y, o[1]);
        o[2] = fmaf(tj, wa.z, o[2]);
        o[3] = fmaf(tj, wa.w, o[3]);
        o[4] = fmaf(tj, wb.x, o[4]);
        o[5] = fmaf(tj, wb.y, o[5]);
        o[6] = fmaf(tj, wb.z, o[6]);
        o[7] = fmaf(tj, wb.w, o[7]);
    }

    float4* op = (float4*)(out + (size_t)i * NACT);
    op[0] = make_float4(o[0], o[1], o[2], o[3]);
    op[1] = make_float4(o[4], o[5], o[6], o[7]);
}

extern "C" void kernel_launch(void* const* d_in, const int* in_sizes, int n_in,
                              void* d_out, int out_size, void* d_ws, size_t ws_size,
                              hipStream_t stream) {
    const float* x  = (const float*)d_in[0];
    const int*   ei = (const int*)d_in[1];
    const float* W1 = (const float*)d_in[2];
    const float* b1 = (const float*)d_in[3];
    const float* W2 = (const float*)d_in[4];
    const float* b2 = (const float*)d_in[5];
    float* out = (float*)d_out;

    const int n = in_sizes[0] / NOBS;   // 100000
    const int e = in_sizes[1] / 2;      // 1600000

    // ws layout: deg[n] | dinv[n] | agg[n*32]  (13.6 MB)
    char* ws = (char*)d_ws;
    float* deg  = (float*)ws;
    float* dinv = (float*)(ws + (size_t)n * 4);
    float* agg  = (float*)(ws + (size_t)n * 8);   // offset 800000 -> 16B aligned

    k_deg_init<<<(n + 255) / 256, 256, 0, stream>>>(deg, n);
    k_deg_count<<<(e + 255) / 256, 256, 0, stream>>>(ei, deg, e);
    long long t_init = (long long)n * NOBS;
    k_init_agg<<<(int)((t_init + 255) / 256), 256, 0, stream>>>(x, deg, dinv, agg, n);
    long long t_scat = (long long)e * NOBS;
    k_scatter<<<(int)((t_scat + 255) / 256), 256, 0, stream>>>(ei, x, dinv, agg, e);
    k_final<<<(n + 255) / 256, 256, 0, stream>>>(agg, W1, b1, W2, b2, out, n);
}

// Round 2
// 296.176 us; speedup vs baseline: 4.1081x; 4.1081x over previous
//
#include <hip/hip_runtime.h>
#include <math.h>

// GCNConv QNet: out = tanh( (segsum(x[src]*norm, dst) + selfloop) @ W1 + b1 ) @ W2 + b2
// with norm = dinv[src]*dinv[dst], dinv = rsqrt(in_degree + 1).
// Aggregation done in 32-dim obs space (W1 applied AFTER segment_sum — linearity).

#define NOBS 32
#define NMID 64
#define NACT 8

// Detect whether edge_index arrived as int64 (reference dtype) or int32.
// For little-endian int64 values in [0, 2^31), every odd 32-bit word is zero.
__device__ __forceinline__ bool edges_i64(const int* ei) {
    return (ei[1] | ei[3] | ei[5] | ei[7]) == 0;
}

__device__ __forceinline__ void load_edge(const int* ei, bool i64, long long e,
                                          long long idx, int& s, int& d) {
    if (i64) {
        const long long* e64 = (const long long*)ei;
        s = (int)e64[idx];
        d = (int)e64[e + idx];
    } else {
        s = ei[idx];
        d = ei[e + idx];
    }
}

__global__ void k_deg_init(float* __restrict__ deg, int n) {
    int i = blockIdx.x * blockDim.x + threadIdx.x;
    if (i < n) deg[i] = 1.0f;  // self-loop
}

__global__ void k_deg_count(const int* __restrict__ ei, float* __restrict__ deg, int e) {
    long long t = (long long)blockIdx.x * blockDim.x + threadIdx.x;
    if (t >= e) return;
    bool i64 = edges_i64(ei);
    int d;
    if (i64) d = (int)((const long long*)ei)[(long long)e + t];
    else     d = ei[(long long)e + t];
    atomicAdd(&deg[d], 1.0f);
}

// dinv = rsqrt(deg); agg[i][:] = x[i][:] * dinv[i]^2  (self-loop message)
__global__ void k_init_agg(const float* __restrict__ x, const float* __restrict__ deg,
                           float* __restrict__ dinv, float* __restrict__ agg, int n) {
    long long t = (long long)blockIdx.x * blockDim.x + threadIdx.x;
    if (t >= (long long)n * NOBS) return;
    int i = (int)(t >> 5);
    float r = rsqrtf(deg[i]);
    if ((t & 31) == 0) dinv[i] = r;
    agg[t] = x[t] * (r * r);
}

// 32 lanes per edge: coalesced gather of x[src] row + coalesced atomic burst to agg[dst]
__global__ void k_scatter(const int* __restrict__ ei, const float* __restrict__ x,
                          const float* __restrict__ dinv, float* __restrict__ agg, int e) {
    long long t = (long long)blockIdx.x * blockDim.x + threadIdx.x;
    if (t >= (long long)e * NOBS) return;
    int lane = (int)(t & 31);
    long long eidx = t >> 5;
    bool i64 = edges_i64(ei);
    int s, d;
    load_edge(ei, i64, e, eidx, s, d);
    float w = dinv[s] * dinv[d];
    float v = x[(long long)s * NOBS + lane] * w;
    atomicAdd(&agg[(long long)d * NOBS + lane], v);
}

// Per-node dense epilogue: out = tanh(agg @ W1 + b1) @ W2 + b2.
// NO per-thread arrays: agg row in 8 named float4s, W1 transposed in LDS
// (column j contiguous -> broadcast ds_read_b128), one m_j at a time.
__global__ __launch_bounds__(256) void k_final(
        const float* __restrict__ agg, const float* __restrict__ W1,
        const float* __restrict__ b1, const float* __restrict__ W2,
        const float* __restrict__ b2, float* __restrict__ out, int n) {
    __shared__ float sW1T[NMID * NOBS];  // sW1T[j*32+c] = W1[c][j]; 8 KB
    __shared__ float sW2[NMID * NACT];   // 2 KB
    __shared__ float sb1[NMID];
    __shared__ float sb2[NACT];
    for (int t = threadIdx.x; t < NMID * NOBS; t += 256) {
        int j = t >> 5, c = t & 31;          // contiguous LDS write, no bank conflict
        sW1T[t] = W1[c * NMID + j];          // scattered 4B global reads of 8KB, L1/L2-hit
    }
    for (int t = threadIdx.x; t < NMID * NACT; t += 256) sW2[t] = W2[t];
    if (threadIdx.x < NMID) sb1[threadIdx.x] = b1[threadIdx.x];
    if (threadIdx.x < NACT) sb2[threadIdx.x] = b2[threadIdx.x];
    __syncthreads();

    int i = blockIdx.x * 256 + threadIdx.x;
    if (i >= n) return;

    const float4* a4 = (const float4*)(agg + (size_t)i * NOBS);
    float4 A0 = a4[0], A1 = a4[1], A2 = a4[2], A3 = a4[3];
    float4 A4 = a4[4], A5 = a4[5], A6 = a4[6], A7 = a4[7];

    float4 oa = *(const float4*)(sb2);
    float4 ob = *(const float4*)(sb2 + 4);

    for (int j = 0; j < NMID; ++j) {
        const float4* w = (const float4*)(sW1T + j * NOBS);  // broadcast reads
        float4 w0 = w[0], w1 = w[1], w2 = w[2], w3 = w[3];
        float4 w4 = w[4], w5 = w[5], w6 = w[6], w7 = w[7];
        float ma = sb1[j], mb = 0.f, mc = 0.f, md = 0.f;
        ma = fmaf(A0.x, w0.x, ma); ma = fmaf(A0.y, w0.y, ma);
        ma = fmaf(A0.z, w0.z, ma); ma = fmaf(A0.w, w0.w, ma);
        mb = fmaf(A1.x, w1.x, mb); mb = fmaf(A1.y, w1.y, mb);
        mb = fmaf(A1.z, w1.z, mb); mb = fmaf(A1.w, w1.w, mb);
        mc = fmaf(A2.x, w2.x, mc); mc = fmaf(A2.y, w2.y, mc);
        mc = fmaf(A2.z, w2.z, mc); mc = fmaf(A2.w, w2.w, mc);
        md = fmaf(A3.x, w3.x, md); md = fmaf(A3.y, w3.y, md);
        md = fmaf(A3.z, w3.z, md); md = fmaf(A3.w, w3.w, md);
        ma = fmaf(A4.x, w4.x, ma); ma = fmaf(A4.y, w4.y, ma);
        ma = fmaf(A4.z, w4.z, ma); ma = fmaf(A4.w, w4.w, ma);
        mb = fmaf(A5.x, w5.x, mb); mb = fmaf(A5.y, w5.y, mb);
        mb = fmaf(A5.z, w5.z, mb); mb = fmaf(A5.w, w5.w, mb);
        mc = fmaf(A6.x, w6.x, mc); mc = fmaf(A6.y, w6.y, mc);
        mc = fmaf(A6.z, w6.z, mc); mc = fmaf(A6.w, w6.w, mc);
        md = fmaf(A7.x, w7.x, md); md = fmaf(A7.y, w7.y, md);
        md = fmaf(A7.z, w7.z, md); md = fmaf(A7.w, w7.w, md);
        float m = (ma + mb) + (mc + md);
        float tj = tanhf(m);
        const float4* wp = (const float4*)(sW2 + j * NACT);
        float4 wa = wp[0], wb = wp[1];
        oa.x = fmaf(tj, wa.x, oa.x); oa.y = fmaf(tj, wa.y, oa.y);
        oa.z = fmaf(tj, wa.z, oa.z); oa.w = fmaf(tj, wa.w, oa.w);
        ob.x = fmaf(tj, wb.x, ob.x); ob.y = fmaf(tj, wb.y, ob.y);
        ob.z = fmaf(tj, wb.z, ob.z); ob.w = fmaf(tj, wb.w, ob.w);
    }

    float4* op = (float4*)(out + (size_t)i * NACT);
    op[0] = oa;
    op[1] = ob;
}

extern "C" void kernel_launch(void* const* d_in, const int* in_sizes, int n_in,
                              void* d_out, int out_size, void* d_ws, size_t ws_size,
                              hipStream_t stream) {
    const float* x  = (const float*)d_in[0];
    const int*   ei = (const int*)d_in[1];
    const float* W1 = (const float*)d_in[2];
    const float* b1 = (const float*)d_in[3];
    const float* W2 = (const float*)d_in[4];
    const float* b2 = (const float*)d_in[5];
    float* out = (float*)d_out;

    const int n = in_sizes[0] / NOBS;   // 100000
    const int e = in_sizes[1] / 2;      // 1600000

    // ws layout: deg[n] | dinv[n] | agg[n*32]  (13.6 MB)
    char* ws = (char*)d_ws;
    float* deg  = (float*)ws;
    float* dinv = (float*)(ws + (size_t)n * 4);
    float* agg  = (float*)(ws + (size_t)n * 8);   // offset 800000 -> 16B aligned

    k_deg_init<<<(n + 255) / 256, 256, 0, stream>>>(deg, n);
    k_deg_count<<<(e + 255) / 256, 256, 0, stream>>>(ei, deg, e);
    long long t_init = (long long)n * NOBS;
    k_init_agg<<<(int)((t_init + 255) / 256), 256, 0, stream>>>(x, deg, dinv, agg, n);
    long long t_scat = (long long)e * NOBS;
    k_scatter<<<(int)((t_scat + 255) / 256), 256, 0, stream>>>(ei, x, dinv, agg, e);
    k_final<<<(n + 255) / 256, 256, 0, stream>>>(agg, W1, b1, W2, b2, out, n);
}

// Round 3
// 285.139 us; speedup vs baseline: 4.2671x; 1.0387x over previous
//
#include <hip/hip_runtime.h>
#include <math.h>

// GCNConv QNet: out = tanh( (segsum(x[src]*norm, dst) + selfloop) @ W1 + b1 ) @ W2 + b2
// with norm = dinv[src]*dinv[dst], dinv = rsqrt(in_degree + 1).
// Aggregation in 32-dim obs space (W1 applied AFTER segment_sum — linearity).
// R3: CSR build on device + pull-style gather (no f32 atomics on the 128B rows).

#define NOBS 32
#define NMID 64
#define NACT 8

// Detect whether edge_index arrived as int64 (reference dtype) or int32.
// For little-endian int64 values in [0, 2^31), every odd 32-bit word is zero.
__device__ __forceinline__ bool edges_i64(const int* ei) {
    return (ei[1] | ei[3] | ei[5] | ei[7]) == 0;
}

__device__ __forceinline__ int load_dst(const int* ei, bool i64, long long e, long long t) {
    return i64 ? (int)((const long long*)ei)[e + t] : ei[e + t];
}
__device__ __forceinline__ int load_src(const int* ei, bool i64, long long t) {
    return i64 ? (int)((const long long*)ei)[t] : ei[t];
}

__global__ void k_zero(int* __restrict__ p, int n) {
    int i = blockIdx.x * blockDim.x + threadIdx.x;
    if (i < n) p[i] = 0;
}

__global__ void k_hist(const int* __restrict__ ei, int* __restrict__ ideg, int e) {
    long long t = (long long)blockIdx.x * blockDim.x + threadIdx.x;
    if (t >= e) return;
    bool i64 = edges_i64(ei);
    atomicAdd(&ideg[load_dst(ei, i64, e, t)], 1);
}

// Per-block exclusive scan (256 elems/block) + block totals
__global__ __launch_bounds__(256) void k_scan1(const int* __restrict__ ideg,
                                               int* __restrict__ row_start,
                                               int* __restrict__ bsum, int n) {
    __shared__ int s[256];
    int i = blockIdx.x * 256 + threadIdx.x;
    int v = (i < n) ? ideg[i] : 0;
    s[threadIdx.x] = v;
    __syncthreads();
    for (int off = 1; off < 256; off <<= 1) {
        int t = (threadIdx.x >= off) ? s[threadIdx.x - off] : 0;
        __syncthreads();
        s[threadIdx.x] += t;
        __syncthreads();
    }
    if (i < n) row_start[i] = s[threadIdx.x] - v;  // exclusive
    if (threadIdx.x == 255) bsum[blockIdx.x] = s[255];
}

// Single-block exclusive scan of block sums (nb <= 512)
__global__ __launch_bounds__(512) void k_scan2(int* __restrict__ bsum, int nb) {
    __shared__ int s[512];
    int v = (threadIdx.x < nb) ? bsum[threadIdx.x] : 0;
    s[threadIdx.x] = v;
    __syncthreads();
    for (int off = 1; off < 512; off <<= 1) {
        int t = (threadIdx.x >= off) ? s[threadIdx.x - off] : 0;
        __syncthreads();
        s[threadIdx.x] += t;
        __syncthreads();
    }
    if (threadIdx.x < nb) bsum[threadIdx.x] = s[threadIdx.x] - v;
}

// Finalize row_start, init cursor copy, compute dinv = rsqrt(ideg+1)
__global__ void k_scan3(int* __restrict__ row_start, const int* __restrict__ bsum,
                        int* __restrict__ cursor, const int* __restrict__ ideg,
                        float* __restrict__ dinv, int n) {
    int i = blockIdx.x * blockDim.x + threadIdx.x;
    if (i >= n) return;
    int rs = row_start[i] + bsum[i >> 8];
    row_start[i] = rs;
    cursor[i] = rs;
    dinv[i] = rsqrtf((float)(ideg[i] + 1));
}

// Scatter edge sources into CSR slots (int atomics on cursors only)
__global__ void k_fill(const int* __restrict__ ei, int* __restrict__ cursor,
                       int* __restrict__ csr, int e) {
    long long t = (long long)blockIdx.x * blockDim.x + threadIdx.x;
    if (t >= e) return;
    bool i64 = edges_i64(ei);
    int s = load_src(ei, i64, t);
    int d = load_dst(ei, i64, e, t);
    int pos = atomicAdd(&cursor[d], 1);
    csr[pos] = s;
}

// Pull aggregation: one wave (64 lanes) per node. Lanes split into two halves
// of 32; each half walks alternate edges with a 2-acc unroll (4 gathers in
// flight per wave). agg[i] = dinv_i * (sum_e dinv_s * x_s + dinv_i * x_i).
__global__ __launch_bounds__(256) void k_gather(
        const int* __restrict__ csr, const int* __restrict__ row_start,
        const int* __restrict__ ideg, const float* __restrict__ dinv,
        const float* __restrict__ x, float* __restrict__ agg, int n) {
    int wid = (int)(((long long)blockIdx.x * 256 + threadIdx.x) >> 6);
    if (wid >= n) return;  // uniform per wave
    int lane = threadIdx.x & 63;
    int half = lane >> 5, c = lane & 31;
    float di = dinv[wid];
    float acc = 0.f, acc2 = 0.f;
    if (!half) acc = x[(size_t)wid * NOBS + c] * di;  // self-loop (x dinv_i)
    int beg = row_start[wid];
    int end = beg + ideg[wid];
    int k = beg + half;
    for (; k + 2 < end; k += 4) {
        int s0 = csr[k], s1 = csr[k + 2];
        acc  = fmaf(dinv[s0], x[(size_t)s0 * NOBS + c], acc);
        acc2 = fmaf(dinv[s1], x[(size_t)s1 * NOBS + c], acc2);
    }
    if (k < end) {
        int s0 = csr[k];
        acc = fmaf(dinv[s0], x[(size_t)s0 * NOBS + c], acc);
    }
    acc += acc2;
    acc += __shfl_xor(acc, 32);
    if (!half) agg[(size_t)wid * NOBS + c] = acc * di;
}

// Per-node dense epilogue: out = tanh(agg @ W1 + b1) @ W2 + b2.
// No per-thread arrays: agg row in 8 named float4s, W1 transposed in LDS.
__global__ __launch_bounds__(256) void k_final(
        const float* __restrict__ agg, const float* __restrict__ W1,
        const float* __restrict__ b1, const float* __restrict__ W2,
        const float* __restrict__ b2, float* __restrict__ out, int n) {
    __shared__ float sW1T[NMID * NOBS];  // sW1T[j*32+c] = W1[c][j]; 8 KB
    __shared__ float sW2[NMID * NACT];   // 2 KB
    __shared__ float sb1[NMID];
    __shared__ float sb2[NACT];
    for (int t = threadIdx.x; t < NMID * NOBS; t += 256) {
        int j = t >> 5, c = t & 31;
        sW1T[t] = W1[c * NMID + j];
    }
    for (int t = threadIdx.x; t < NMID * NACT; t += 256) sW2[t] = W2[t];
    if (threadIdx.x < NMID) sb1[threadIdx.x] = b1[threadIdx.x];
    if (threadIdx.x < NACT) sb2[threadIdx.x] = b2[threadIdx.x];
    __syncthreads();

    int i = blockIdx.x * 256 + threadIdx.x;
    if (i >= n) return;

    const float4* a4 = (const float4*)(agg + (size_t)i * NOBS);
    float4 A0 = a4[0], A1 = a4[1], A2 = a4[2], A3 = a4[3];
    float4 A4 = a4[4], A5 = a4[5], A6 = a4[6], A7 = a4[7];

    float4 oa = *(const float4*)(sb2);
    float4 ob = *(const float4*)(sb2 + 4);

    for (int j = 0; j < NMID; ++j) {
        const float4* w = (const float4*)(sW1T + j * NOBS);
        float4 w0 = w[0], w1 = w[1], w2 = w[2], w3 = w[3];
        float4 w4 = w[4], w5 = w[5], w6 = w[6], w7 = w[7];
        float ma = sb1[j], mb = 0.f, mc = 0.f, md = 0.f;
        ma = fmaf(A0.x, w0.x, ma); ma = fmaf(A0.y, w0.y, ma);
        ma = fmaf(A0.z, w0.z, ma); ma = fmaf(A0.w, w0.w, ma);
        mb = fmaf(A1.x, w1.x, mb); mb = fmaf(A1.y, w1.y, mb);
        mb = fmaf(A1.z, w1.z, mb); mb = fmaf(A1.w, w1.w, mb);
        mc = fmaf(A2.x, w2.x, mc); mc = fmaf(A2.y, w2.y, mc);
        mc = fmaf(A2.z, w2.z, mc); mc = fmaf(A2.w, w2.w, mc);
        md = fmaf(A3.x, w3.x, md); md = fmaf(A3.y, w3.y, md);
        md = fmaf(A3.z, w3.z, md); md = fmaf(A3.w, w3.w, md);
        ma = fmaf(A4.x, w4.x, ma); ma = fmaf(A4.y, w4.y, ma);
        ma = fmaf(A4.z, w4.z, ma); ma = fmaf(A4.w, w4.w, ma);
        mb = fmaf(A5.x, w5.x, mb); mb = fmaf(A5.y, w5.y, mb);
        mb = fmaf(A5.z, w5.z, mb); mb = fmaf(A5.w, w5.w, mb);
        mc = fmaf(A6.x, w6.x, mc); mc = fmaf(A6.y, w6.y, mc);
        mc = fmaf(A6.z, w6.z, mc); mc = fmaf(A6.w, w6.w, mc);
        md = fmaf(A7.x, w7.x, md); md = fmaf(A7.y, w7.y, md);
        md = fmaf(A7.z, w7.z, md); md = fmaf(A7.w, w7.w, md);
        float m = (ma + mb) + (mc + md);
        float tj = tanhf(m);
        const float4* wp = (const float4*)(sW2 + j * NACT);
        float4 wa = wp[0], wb = wp[1];
        oa.x = fmaf(tj, wa.x, oa.x); oa.y = fmaf(tj, wa.y, oa.y);
        oa.z = fmaf(tj, wa.z, oa.z); oa.w = fmaf(tj, wa.w, oa.w);
        ob.x = fmaf(tj, wb.x, ob.x); ob.y = fmaf(tj, wb.y, ob.y);
        ob.z = fmaf(tj, wb.z, ob.z); ob.w = fmaf(tj, wb.w, ob.w);
    }

    float4* op = (float4*)(out + (size_t)i * NACT);
    op[0] = oa;
    op[1] = ob;
}

extern "C" void kernel_launch(void* const* d_in, const int* in_sizes, int n_in,
                              void* d_out, int out_size, void* d_ws, size_t ws_size,
                              hipStream_t stream) {
    const float* x  = (const float*)d_in[0];
    const int*   ei = (const int*)d_in[1];
    const float* W1 = (const float*)d_in[2];
    const float* b1 = (const float*)d_in[3];
    const float* W2 = (const float*)d_in[4];
    const float* b2 = (const float*)d_in[5];
    float* out = (float*)d_out;

    const int n = in_sizes[0] / NOBS;   // 100000
    const int e = in_sizes[1] / 2;      // 1600000
    const int nb = (n + 255) / 256;     // 391 scan blocks

    // ws layout (bytes):
    //   ideg      int[n]      @ 0
    //   row_start int[n]      @ n*4
    //   cursor    int[n]      @ n*8
    //   dinv      f32[n]      @ n*12
    //   bsum      int[512]    @ n*16
    //   csr       int[e]      @ n*16 + 2048
    //   agg       f32[n*32]   @ n*16 + 2048 + e*4   (16B aligned for n,e mult of 4)
    char* ws = (char*)d_ws;
    int*   ideg      = (int*)ws;
    int*   row_start = (int*)(ws + (size_t)n * 4);
    int*   cursor    = (int*)(ws + (size_t)n * 8);
    float* dinv      = (float*)(ws + (size_t)n * 12);
    int*   bsum      = (int*)(ws + (size_t)n * 16);
    int*   csr       = (int*)(ws + (size_t)n * 16 + 2048);
    float* agg       = (float*)(ws + (size_t)n * 16 + 2048 + (size_t)e * 4);

    k_zero<<<nb, 256, 0, stream>>>(ideg, n);
    k_hist<<<(e + 255) / 256, 256, 0, stream>>>(ei, ideg, e);
    k_scan1<<<nb, 256, 0, stream>>>(ideg, row_start, bsum, n);
    k_scan2<<<1, 512, 0, stream>>>(bsum, nb);
    k_scan3<<<nb, 256, 0, stream>>>(row_start, bsum, cursor, ideg, dinv, n);
    k_fill<<<(e + 255) / 256, 256, 0, stream>>>(ei, cursor, csr, e);
    long long t_gather = (long long)n * 64;
    k_gather<<<(int)((t_gather + 255) / 256), 256, 0, stream>>>(
        csr, row_start, ideg, dinv, x, agg, n);
    k_final<<<nb, 256, 0, stream>>>(agg, W1, b1, W2, b2, out, n);
}